// Round 1
// baseline (177.463 us; speedup 1.0000x reference)
//
#include <hip/hip_runtime.h>
#include <hip/hip_bf16.h>
#include <stdint.h>

#define C_DIM   256
#define L_ANCH  8
#define M_INST  64
#define NPIX    32768
#define TILE_M  64
#define PAD     8
#define LDSTR   (C_DIM + PAD)   // 264 bf16 per row

typedef __attribute__((ext_vector_type(8))) short  short8;   // 8 x bf16
typedef __attribute__((ext_vector_type(4))) float  float4v;  // MFMA C/D

__device__ __forceinline__ float bf2f(unsigned short b) {
    union { unsigned u; float f; } x; x.u = ((unsigned)b) << 16; return x.f;
}
__device__ __forceinline__ unsigned short f2bf(float f) {
    union { unsigned u; float f; } x; x.f = f;
    unsigned u = x.u;
    unsigned r = (u + 0x7FFFu + ((u >> 16) & 1u)) >> 16;  // RNE
    return (unsigned short)r;
}

// ---------------------------------------------------------------------------
// prep: blocks 0..63  -> K/V projection for anchor m=blockIdx (bf16 out)
//       blocks 64..95 -> convert Wq (in_proj_w rows 0..255) and out_w to bf16
// ---------------------------------------------------------------------------
__global__ __launch_bounds__(256) void prep_kernel(
    const float* __restrict__ anchors, const float* __restrict__ in_proj_w,
    const float* __restrict__ in_proj_b, const float* __restrict__ out_w,
    unsigned short* __restrict__ Kb, unsigned short* __restrict__ Vb,
    unsigned short* __restrict__ Wqb, unsigned short* __restrict__ Owb)
{
    __shared__ float a_lds[L_ANCH][C_DIM];
    const int b = blockIdx.x, t = threadIdx.x;
    if (b < M_INST) {
        const float* ap = anchors + (size_t)b * (L_ANCH * C_DIM);
        for (int i = t; i < L_ANCH * C_DIM; i += 256)
            a_lds[i >> 8][i & 255] = ap[i];
        __syncthreads();
        const int d = t;  // 256 output dims
        const float* wk = in_proj_w + (size_t)(C_DIM + d) * C_DIM;
        const float* wv = in_proj_w + (size_t)(2 * C_DIM + d) * C_DIM;
        float accK[L_ANCH], accV[L_ANCH];
#pragma unroll
        for (int l = 0; l < L_ANCH; ++l) { accK[l] = 0.f; accV[l] = 0.f; }
        for (int c = 0; c < C_DIM; ++c) {
            float k = wk[c], v = wv[c];
#pragma unroll
            for (int l = 0; l < L_ANCH; ++l) {
                float a = a_lds[l][c];
                accK[l] += a * k;
                accV[l] += a * v;
            }
        }
        const float bk = in_proj_b[C_DIM + d];
        const float bv = in_proj_b[2 * C_DIM + d];
#pragma unroll
        for (int l = 0; l < L_ANCH; ++l) {
            Kb[(b * L_ANCH + l) * C_DIM + d] = f2bf(accK[l] + bk);
            Vb[(b * L_ANCH + l) * C_DIM + d] = f2bf(accV[l] + bv);
        }
    } else {
        // 32 blocks x 256 threads x 16 elems = 131072 = 2 * 65536
        const int g = (b - M_INST) * 256 + t;
        const int e0 = g * 16;
#pragma unroll 4
        for (int e = e0; e < e0 + 16; ++e) {
            if (e < 65536) Wqb[e] = f2bf(in_proj_w[e]);
            else           Owb[e - 65536] = f2bf(out_w[e - 65536]);
        }
    }
}

// ---------------------------------------------------------------------------
// fused: per block of 64 pixels:
//   stage F (bf16, LDS) -> GEMM1 (Q = F Wq^T + bq, MFMA) -> Q to LDS bf16 ->
//   attention (4 lanes / pixel, shfl reduce + softmax + broadcast) ->
//   O (bf16) over F buffer -> GEMM2 (O out_w^T) -> out = f + mask*(.+out_b)
// ---------------------------------------------------------------------------
__global__ __launch_bounds__(256, 2) void fused_kernel(
    const float* __restrict__ features, const int* __restrict__ inst,
    const float* __restrict__ in_proj_b, const float* __restrict__ out_b,
    const unsigned short* __restrict__ Wqb, const unsigned short* __restrict__ Owb,
    const unsigned short* __restrict__ Kb, const unsigned short* __restrict__ Vb,
    float* __restrict__ out)
{
    __shared__ unsigned short Fbuf[TILE_M * LDSTR];  // F tile, later O tile
    __shared__ unsigned short Qbuf[TILE_M * LDSTR];  // Q tile (bf16)

    const int t = threadIdx.x;
    const int n0 = blockIdx.x * TILE_M;

    // ---- stage F tile as bf16 (coalesced float4 per lane) ----
#pragma unroll
    for (int i = 0; i < 16; ++i) {
        int idx = t + i * 256;            // float4-chunk id, 0..4095
        int row = idx >> 6, ch = idx & 63;
        float4 f = *((const float4*)(features + (size_t)(n0 + row) * C_DIM) + ch);
        ushort4 v;
        v.x = f2bf(f.x); v.y = f2bf(f.y); v.z = f2bf(f.z); v.w = f2bf(f.w);
        *(ushort4*)&Fbuf[row * LDSTR + ch * 4] = v;
    }
    __syncthreads();

    const int wave = t >> 6, lane = t & 63;
    const int r16 = lane & 15, quad = lane >> 4;

    // ---- GEMM1: Q[0:64][wave*64 .. wave*64+63] ----
    float4v acc[4][4];
#pragma unroll
    for (int mt = 0; mt < 4; ++mt)
#pragma unroll
        for (int nt = 0; nt < 4; ++nt)
#pragma unroll
            for (int r = 0; r < 4; ++r) acc[mt][nt][r] = 0.f;

    for (int ks = 0; ks < 8; ++ks) {
        const int c0 = ks * 32 + quad * 8;
        short8 afr[4], bfr[4];
#pragma unroll
        for (int mt = 0; mt < 4; ++mt)
            afr[mt] = *(const short8*)&Fbuf[(mt * 16 + r16) * LDSTR + c0];
#pragma unroll
        for (int nt = 0; nt < 4; ++nt) {
            int drow = wave * 64 + nt * 16 + r16;
            bfr[nt] = *(const short8*)&Wqb[drow * C_DIM + c0];
        }
#pragma unroll
        for (int mt = 0; mt < 4; ++mt)
#pragma unroll
            for (int nt = 0; nt < 4; ++nt)
                acc[mt][nt] = __builtin_amdgcn_mfma_f32_16x16x32_bf16(
                    afr[mt], bfr[nt], acc[mt][nt], 0, 0, 0);
    }

    // ---- add bq, store Q to LDS (bf16) ----
#pragma unroll
    for (int nt = 0; nt < 4; ++nt) {
        const int col = wave * 64 + nt * 16 + r16;
        const float bq = in_proj_b[col];
#pragma unroll
        for (int mt = 0; mt < 4; ++mt)
#pragma unroll
            for (int r = 0; r < 4; ++r) {
                int row = mt * 16 + quad * 4 + r;
                Qbuf[row * LDSTR + col] = f2bf(acc[mt][nt][r] + bq);
            }
    }
    __syncthreads();

    // ---- attention: 4 lanes per pixel, 64 cols each ----
    const int p = t >> 2, s = t & 3;
    const int n = n0 + p;
    const int lab = inst[n];
    const int aidx = max(lab - 1, 0);
    const unsigned short* Kp = Kb + (size_t)aidx * L_ANCH * C_DIM;
    const unsigned short* Vp = Vb + (size_t)aidx * L_ANCH * C_DIM;

    float sc[L_ANCH];
#pragma unroll
    for (int l = 0; l < L_ANCH; ++l) {
        float partial = 0.f;
#pragma unroll
        for (int ch = 0; ch < 8; ++ch) {
            int cbase = s * 64 + ch * 8;
            short8 kv = *(const short8*)&Kp[l * C_DIM + cbase];
            short8 qv = *(const short8*)&Qbuf[p * LDSTR + cbase];
#pragma unroll
            for (int j = 0; j < 8; ++j)
                partial += bf2f(((const unsigned short*)&qv)[j]) *
                           bf2f(((const unsigned short*)&kv)[j]);
        }
        partial += __shfl_down(partial, 1);
        partial += __shfl_down(partial, 2);
        sc[l] = partial;                        // valid on s==0
    }

    float attn[L_ANCH];
    if (s == 0) {
        const float scale = 0.0625f;            // 1/sqrt(256)
        float mx = -1e30f;
#pragma unroll
        for (int l = 0; l < L_ANCH; ++l) { sc[l] *= scale; mx = fmaxf(mx, sc[l]); }
        float sum = 0.f;
#pragma unroll
        for (int l = 0; l < L_ANCH; ++l) { attn[l] = __expf(sc[l] - mx); sum += attn[l]; }
        float inv = 1.f / sum;
#pragma unroll
        for (int l = 0; l < L_ANCH; ++l) attn[l] *= inv;
    }
    const int base_lane = (t & 63) & ~3;
    float a_bc[L_ANCH];
#pragma unroll
    for (int l = 0; l < L_ANCH; ++l) a_bc[l] = __shfl(attn[l], base_lane);

    // ---- O = attn @ V, write bf16 over F buffer ----
#pragma unroll
    for (int ch = 0; ch < 8; ++ch) {
        int cbase = s * 64 + ch * 8;
        float o8[8];
#pragma unroll
        for (int j = 0; j < 8; ++j) o8[j] = 0.f;
#pragma unroll
        for (int l = 0; l < L_ANCH; ++l) {
            short8 vv = *(const short8*)&Vp[l * C_DIM + cbase];
            float av = a_bc[l];
#pragma unroll
            for (int j = 0; j < 8; ++j)
                o8[j] += av * bf2f(((const unsigned short*)&vv)[j]);
        }
        unsigned short pk[8];
#pragma unroll
        for (int j = 0; j < 8; ++j) pk[j] = f2bf(o8[j]);
        *(short8*)&Fbuf[p * LDSTR + cbase] = *(const short8*)pk;
    }
    __syncthreads();

    // ---- GEMM2: OUT = O @ out_w^T ----
    float4v acc2[4][4];
#pragma unroll
    for (int mt = 0; mt < 4; ++mt)
#pragma unroll
        for (int nt = 0; nt < 4; ++nt)
#pragma unroll
            for (int r = 0; r < 4; ++r) acc2[mt][nt][r] = 0.f;

    for (int ks = 0; ks < 8; ++ks) {
        const int c0 = ks * 32 + quad * 8;
        short8 afr[4], bfr[4];
#pragma unroll
        for (int mt = 0; mt < 4; ++mt)
            afr[mt] = *(const short8*)&Fbuf[(mt * 16 + r16) * LDSTR + c0];
#pragma unroll
        for (int nt = 0; nt < 4; ++nt) {
            int drow = wave * 64 + nt * 16 + r16;
            bfr[nt] = *(const short8*)&Owb[drow * C_DIM + c0];
        }
#pragma unroll
        for (int mt = 0; mt < 4; ++mt)
#pragma unroll
            for (int nt = 0; nt < 4; ++nt)
                acc2[mt][nt] = __builtin_amdgcn_mfma_f32_16x16x32_bf16(
                    afr[mt], bfr[nt], acc2[mt][nt], 0, 0, 0);
    }

    // ---- epilogue: out = f + mask * (acc2 + out_b) ----
#pragma unroll
    for (int nt = 0; nt < 4; ++nt) {
        const int col = wave * 64 + nt * 16 + r16;
        const float bo = out_b[col];
#pragma unroll
        for (int mt = 0; mt < 4; ++mt)
#pragma unroll
            for (int r = 0; r < 4; ++r) {
                int row = mt * 16 + quad * 4 + r;
                int nn = n0 + row;
                size_t gi = (size_t)nn * C_DIM + col;
                float fv = features[gi];
                float val = acc2[mt][nt][r] + bo;
                out[gi] = fv + ((inst[nn] > 0) ? val : 0.f);
            }
    }
}

// ---------------------------------------------------------------------------
extern "C" void kernel_launch(void* const* d_in, const int* in_sizes, int n_in,
                              void* d_out, int out_size, void* d_ws, size_t ws_size,
                              hipStream_t stream) {
    const float* anchors   = (const float*)d_in[0];
    const float* features  = (const float*)d_in[1];
    const int*   inst      = (const int*)d_in[2];
    const float* in_proj_w = (const float*)d_in[3];
    const float* in_proj_b = (const float*)d_in[4];
    const float* out_w     = (const float*)d_in[5];
    const float* out_b     = (const float*)d_in[6];
    float* out = (float*)d_out;

    unsigned short* Kb  = (unsigned short*)d_ws;              // 512*256 bf16
    unsigned short* Vb  = Kb  + M_INST * L_ANCH * C_DIM;      // 512*256
    unsigned short* Wqb = Vb  + M_INST * L_ANCH * C_DIM;      // 256*256
    unsigned short* Owb = Wqb + C_DIM * C_DIM;                // 256*256

    prep_kernel<<<96, 256, 0, stream>>>(anchors, in_proj_w, in_proj_b, out_w,
                                        Kb, Vb, Wqb, Owb);
    fused_kernel<<<NPIX / TILE_M, 256, 0, stream>>>(
        features, inst, in_proj_b, out_b, Wqb, Owb, Kb, Vb, out);
}

// Round 2
// 167.706 us; speedup vs baseline: 1.0582x; 1.0582x over previous
//
#include <hip/hip_runtime.h>
#include <stdint.h>

#define C_DIM   256
#define L_ANCH  8
#define M_INST  64
#define NPIX    32768
#define TILE_M  32
#define LDSTR   264      // Fbuf row stride (shorts): 528 B, 16B-aligned rows, 2-way max on frag reads
#define SSTR    260      // stash row stride (shorts): 520 B, 8B-aligned, conflict-free quad writes
#define WSTR    40       // prep W-tile row stride (shorts): 80 B, 16B-aligned

typedef __attribute__((ext_vector_type(8))) short  short8;   // 8 x bf16 (4 VGPRs)
typedef __attribute__((ext_vector_type(4))) float  float4v;  // MFMA C/D

__device__ __forceinline__ float bf2f(unsigned short b) {
    union { unsigned u; float f; } x; x.u = ((unsigned)b) << 16; return x.f;
}
__device__ __forceinline__ unsigned short f2bf(float f) {
    union { unsigned u; float f; } x; x.f = f;
    unsigned u = x.u;
    return (unsigned short)((u + 0x7FFFu + ((u >> 16) & 1u)) >> 16);  // RNE
}
__device__ __forceinline__ ushort4 f4bf(float4 f) {
    ushort4 v; v.x = f2bf(f.x); v.y = f2bf(f.y); v.z = f2bf(f.z); v.w = f2bf(f.w);
    return v;
}

// ---------------------------------------------------------------------------
// prep:
//   blocks 0..31   : K/V = anchors @ {Wk,Wv}^T + b  via MFMA (bf16 out)
//                    b&15 = 32-row anchor tile, b>>4 = mat (0=K,1=V)
//   blocks 32..159 : convert Wq (in_proj_w[0:65536]) and out_w to bf16
// ---------------------------------------------------------------------------
__global__ __launch_bounds__(256) void prep_kernel(
    const float* __restrict__ anchors, const float* __restrict__ in_proj_w,
    const float* __restrict__ in_proj_b, const float* __restrict__ out_w,
    unsigned short* __restrict__ Kb, unsigned short* __restrict__ Vb,
    unsigned short* __restrict__ Wqb, unsigned short* __restrict__ Owb)
{
    __shared__ unsigned short Abuf[TILE_M * LDSTR];     // 16.9 KB
    __shared__ unsigned short Wtile[4][64 * WSTR];      // 20.5 KB (per-wave slices)
    const int b = blockIdx.x, t = threadIdx.x;

    if (b >= 32) {   // ---- weight conversion: 128 blocks x 256 thr x 1 float4
        const int id = (b - 32) * 256 + t;   // 0..32767 float4 chunks
        if (id < 16384) {
            float4 f = *((const float4*)in_proj_w + id);
            *((ushort4*)Wqb + id) = f4bf(f);
        } else {
            float4 f = *((const float4*)out_w + (id - 16384));
            *((ushort4*)Owb + (id - 16384)) = f4bf(f);
        }
        return;
    }

    // ---- K/V MFMA GEMM ----
    const int mat = b >> 4, tile = b & 15, m0 = tile * 32;
    // stage 32 anchor rows (fp32 -> bf16), coalesced
#pragma unroll
    for (int i = 0; i < 8; ++i) {
        int id = t + i * 256;            // 2048 float4 chunks
        int row = id >> 6, c4 = id & 63;
        float4 f = *((const float4*)(anchors + (size_t)(m0 + row) * C_DIM) + c4);
        *(ushort4*)&Abuf[row * LDSTR + c4 * 4] = f4bf(f);
    }
    __syncthreads();

    const int wave = t >> 6, lane = t & 63, r16 = lane & 15, quad = lane >> 4;
    const int wbase = C_DIM + mat * C_DIM + wave * 64;   // W row range for this wave
    unsigned short* Wl = &Wtile[wave][0];

    float4v acc[2][4];
#pragma unroll
    for (int mt = 0; mt < 2; ++mt)
#pragma unroll
        for (int nt = 0; nt < 4; ++nt)
#pragma unroll
            for (int r = 0; r < 4; ++r) acc[mt][nt][r] = 0.f;

    for (int ks = 0; ks < 8; ++ks) {
        // wave-private staging of W[wbase..wbase+64][ks*32..+32] (fp32->bf16)
        const int rr = lane >> 3, cc = lane & 7;
#pragma unroll
        for (int i = 0; i < 8; ++i) {
            int row = rr + i * 8;
            float4 f = *((const float4*)(in_proj_w + (size_t)(wbase + row) * C_DIM + ks * 32) + cc);
            *(ushort4*)&Wl[row * WSTR + cc * 4] = f4bf(f);
        }
        const int c0 = ks * 32 + quad * 8;
        short8 afr[2], bfr[4];
#pragma unroll
        for (int mt = 0; mt < 2; ++mt)
            afr[mt] = *(const short8*)&Abuf[(mt * 16 + r16) * LDSTR + c0];
#pragma unroll
        for (int nt = 0; nt < 4; ++nt)
            bfr[nt] = *(const short8*)&Wl[(nt * 16 + r16) * WSTR + quad * 8];
#pragma unroll
        for (int mt = 0; mt < 2; ++mt)
#pragma unroll
            for (int nt = 0; nt < 4; ++nt)
                acc[mt][nt] = __builtin_amdgcn_mfma_f32_16x16x32_bf16(
                    afr[mt], bfr[nt], acc[mt][nt], 0, 0, 0);
    }

    unsigned short* dst = mat ? Vb : Kb;
#pragma unroll
    for (int nt = 0; nt < 4; ++nt) {
        const int col = wave * 64 + nt * 16 + r16;
        const float bias = in_proj_b[C_DIM + mat * C_DIM + col];
#pragma unroll
        for (int mt = 0; mt < 2; ++mt)
#pragma unroll
            for (int r = 0; r < 4; ++r) {
                int row = m0 + mt * 16 + quad * 4 + r;
                dst[(size_t)row * C_DIM + col] = f2bf(acc[mt][nt][r] + bias);
            }
    }
}

// ---------------------------------------------------------------------------
// fused: 32 pixels/block, 1024 blocks, 4 blocks/CU.
//   stage F(bf16)->GEMM1(Q)->Q over F->attn(8 lanes/pix, O over Q in-place)->
//   GEMM2 -> masked val+bias to stash(bf16) -> vectorized residual epilogue
// ---------------------------------------------------------------------------
__global__ __launch_bounds__(256, 4) void fused_kernel(
    const float* __restrict__ features, const int* __restrict__ inst,
    const float* __restrict__ in_proj_b, const float* __restrict__ out_b,
    const unsigned short* __restrict__ Wqb, const unsigned short* __restrict__ Owb,
    const unsigned short* __restrict__ Kb, const unsigned short* __restrict__ Vb,
    float* __restrict__ out)
{
    __shared__ unsigned short Fbuf[TILE_M * LDSTR];   // F -> Q -> O (16.9 KB)
    __shared__ unsigned short Stash[TILE_M * SSTR];   // masked GEMM2 result (16.6 KB)
    __shared__ int ilab[TILE_M];

    const int t = threadIdx.x;
    const int n0 = blockIdx.x * TILE_M;

    if (t < TILE_M) ilab[t] = inst[n0 + t];

    // ---- stage F tile bf16 (8 float4 per thread, coalesced) ----
#pragma unroll
    for (int i = 0; i < 8; ++i) {
        int id = t + i * 256;            // 2048 float4 chunks
        int row = id >> 6, c4 = id & 63;
        float4 f = *((const float4*)(features + (size_t)(n0 + row) * C_DIM) + c4);
        *(ushort4*)&Fbuf[row * LDSTR + c4 * 4] = f4bf(f);
    }
    __syncthreads();   // (1) F + ilab ready

    const int wave = t >> 6, lane = t & 63, r16 = lane & 15, quad = lane >> 4;

    // ---- GEMM1: Q[32][wave*64..+64] = F @ Wq^T ----
    float4v acc[2][4];
#pragma unroll
    for (int mt = 0; mt < 2; ++mt)
#pragma unroll
        for (int nt = 0; nt < 4; ++nt)
#pragma unroll
            for (int r = 0; r < 4; ++r) acc[mt][nt][r] = 0.f;

    for (int ks = 0; ks < 8; ++ks) {
        const int c0 = ks * 32 + quad * 8;
        short8 afr[2], bfr[4];
#pragma unroll
        for (int mt = 0; mt < 2; ++mt)
            afr[mt] = *(const short8*)&Fbuf[(mt * 16 + r16) * LDSTR + c0];
#pragma unroll
        for (int nt = 0; nt < 4; ++nt) {
            int drow = wave * 64 + nt * 16 + r16;
            bfr[nt] = *(const short8*)&Wqb[(size_t)drow * C_DIM + c0];
        }
#pragma unroll
        for (int mt = 0; mt < 2; ++mt)
#pragma unroll
            for (int nt = 0; nt < 4; ++nt)
                acc[mt][nt] = __builtin_amdgcn_mfma_f32_16x16x32_bf16(
                    afr[mt], bfr[nt], acc[mt][nt], 0, 0, 0);
    }
    __syncthreads();   // (2) all F reads done; buffer reusable for Q

    // ---- Q (+bq) over Fbuf ----
#pragma unroll
    for (int nt = 0; nt < 4; ++nt) {
        const int col = wave * 64 + nt * 16 + r16;
        const float bq = in_proj_b[col];
#pragma unroll
        for (int mt = 0; mt < 2; ++mt)
#pragma unroll
            for (int r = 0; r < 4; ++r) {
                int row = mt * 16 + quad * 4 + r;
                Fbuf[row * LDSTR + col] = f2bf(acc[mt][nt][r] + bq);
            }
    }
    __syncthreads();   // (3) Q ready

    // ---- attention: 8 lanes/pixel, lane s covers 32 channels ----
    const int p = t >> 3, s = t & 7;
    const int aidx = max(ilab[p] - 1, 0);
    const unsigned short* Kp = Kb + (size_t)aidx * L_ANCH * C_DIM;
    const unsigned short* Vp = Vb + (size_t)aidx * L_ANCH * C_DIM;

    float sc[L_ANCH];
#pragma unroll
    for (int l = 0; l < L_ANCH; ++l) {
        float partial = 0.f;
#pragma unroll
        for (int ch = 0; ch < 4; ++ch) {
            int cbase = s * 32 + ch * 8;
            short8 kv = *(const short8*)&Kp[l * C_DIM + cbase];
            short8 qv = *(const short8*)&Fbuf[p * LDSTR + cbase];
#pragma unroll
            for (int j = 0; j < 8; ++j)
                partial += bf2f(((const unsigned short*)&qv)[j]) *
                           bf2f(((const unsigned short*)&kv)[j]);
        }
        partial += __shfl_down(partial, 1);
        partial += __shfl_down(partial, 2);
        partial += __shfl_down(partial, 4);
        sc[l] = partial;                 // valid on s==0
    }

    float attn[L_ANCH];
    if (s == 0) {
        const float scale = 0.0625f;     // 1/sqrt(256)
        float mx = -1e30f;
#pragma unroll
        for (int l = 0; l < L_ANCH; ++l) { sc[l] *= scale; mx = fmaxf(mx, sc[l]); }
        float sum = 0.f;
#pragma unroll
        for (int l = 0; l < L_ANCH; ++l) { attn[l] = __expf(sc[l] - mx); sum += attn[l]; }
        float inv = 1.f / sum;
#pragma unroll
        for (int l = 0; l < L_ANCH; ++l) attn[l] *= inv;
    }
    const int base_lane = lane & ~7;
    float a_bc[L_ANCH];
#pragma unroll
    for (int l = 0; l < L_ANCH; ++l) a_bc[l] = __shfl(attn[l], base_lane);

    // ---- O = attn @ V, in-place over the Q bytes this thread read ----
#pragma unroll
    for (int ch = 0; ch < 4; ++ch) {
        int cbase = s * 32 + ch * 8;
        float o8[8];
#pragma unroll
        for (int j = 0; j < 8; ++j) o8[j] = 0.f;
#pragma unroll
        for (int l = 0; l < L_ANCH; ++l) {
            short8 vv = *(const short8*)&Vp[l * C_DIM + cbase];
            float av = a_bc[l];
#pragma unroll
            for (int j = 0; j < 8; ++j)
                o8[j] += av * bf2f(((const unsigned short*)&vv)[j]);
        }
        unsigned short pk[8];
#pragma unroll
        for (int j = 0; j < 8; ++j) pk[j] = f2bf(o8[j]);
        *(short8*)&Fbuf[p * LDSTR + cbase] = *(const short8*)pk;
    }
    __syncthreads();   // (4) O ready

    // ---- GEMM2: O @ out_w^T ----
    float4v acc2[2][4];
#pragma unroll
    for (int mt = 0; mt < 2; ++mt)
#pragma unroll
        for (int nt = 0; nt < 4; ++nt)
#pragma unroll
            for (int r = 0; r < 4; ++r) acc2[mt][nt][r] = 0.f;

    for (int ks = 0; ks < 8; ++ks) {
        const int c0 = ks * 32 + quad * 8;
        short8 afr[2], bfr[4];
#pragma unroll
        for (int mt = 0; mt < 2; ++mt)
            afr[mt] = *(const short8*)&Fbuf[(mt * 16 + r16) * LDSTR + c0];
#pragma unroll
        for (int nt = 0; nt < 4; ++nt) {
            int drow = wave * 64 + nt * 16 + r16;
            bfr[nt] = *(const short8*)&Owb[(size_t)drow * C_DIM + c0];
        }
#pragma unroll
        for (int mt = 0; mt < 2; ++mt)
#pragma unroll
            for (int nt = 0; nt < 4; ++nt)
                acc2[mt][nt] = __builtin_amdgcn_mfma_f32_16x16x32_bf16(
                    afr[mt], bfr[nt], acc2[mt][nt], 0, 0, 0);
    }

    // ---- masked val+bias -> stash (separate region, no barrier vs GEMM2 reads) ----
#pragma unroll
    for (int nt = 0; nt < 4; ++nt) {
        const int col = wave * 64 + nt * 16 + r16;
        const float bo = out_b[col];
#pragma unroll
        for (int mt = 0; mt < 2; ++mt)
#pragma unroll
            for (int r = 0; r < 4; ++r) {
                int row = mt * 16 + quad * 4 + r;
                float val = (ilab[row] > 0) ? (acc2[mt][nt][r] + bo) : 0.f;
                Stash[row * SSTR + col] = f2bf(val);
            }
    }
    __syncthreads();   // (5) stash ready

    // ---- vectorized residual epilogue ----
#pragma unroll
    for (int i = 0; i < 8; ++i) {
        int id = t + i * 256;
        int row = id >> 6, c4 = id & 63;
        size_t gi = (size_t)(n0 + row) * C_DIM + c4 * 4;
        float4 f = *(const float4*)(features + gi);
        ushort4 v = *(const ushort4*)&Stash[row * SSTR + c4 * 4];
        float4 o;
        o.x = f.x + bf2f(v.x); o.y = f.y + bf2f(v.y);
        o.z = f.z + bf2f(v.z); o.w = f.w + bf2f(v.w);
        *(float4*)(out + gi) = o;
    }
}

// ---------------------------------------------------------------------------
extern "C" void kernel_launch(void* const* d_in, const int* in_sizes, int n_in,
                              void* d_out, int out_size, void* d_ws, size_t ws_size,
                              hipStream_t stream) {
    const float* anchors   = (const float*)d_in[0];
    const float* features  = (const float*)d_in[1];
    const int*   inst      = (const int*)d_in[2];
    const float* in_proj_w = (const float*)d_in[3];
    const float* in_proj_b = (const float*)d_in[4];
    const float* out_w     = (const float*)d_in[5];
    const float* out_b     = (const float*)d_in[6];
    float* out = (float*)d_out;

    unsigned short* Kb  = (unsigned short*)d_ws;              // 512*256 bf16
    unsigned short* Vb  = Kb  + M_INST * L_ANCH * C_DIM;      // 512*256
    unsigned short* Wqb = Vb  + M_INST * L_ANCH * C_DIM;      // 256*256
    unsigned short* Owb = Wqb + C_DIM * C_DIM;                // 256*256

    prep_kernel<<<160, 256, 0, stream>>>(anchors, in_proj_w, in_proj_b, out_w,
                                         Kb, Vb, Wqb, Owb);
    fused_kernel<<<NPIX / TILE_M, 256, 0, stream>>>(
        features, inst, in_proj_b, out_b, Wqb, Owb, Kb, Vb, out);
}